// Round 13
// baseline (188.174 us; speedup 1.0000x reference)
//
#include <hip/hip_runtime.h>
#include <math.h>

#define Hh 128
#define Ww 128
#define HW (128*128)
#define CIN_OFF 196
#define COFF 432

typedef _Float16 half8 __attribute__((ext_vector_type(8)));
typedef _Float16 half4 __attribute__((ext_vector_type(4)));
typedef _Float16 half2v __attribute__((ext_vector_type(2)));
typedef float f32x4 __attribute__((ext_vector_type(4)));

static __device__ __forceinline__ half8 splat8(float v) {
  _Float16 h = (_Float16)v;
  half8 r = {h, h, h, h, h, h, h, h};
  return r;
}

// ---------------- kernel 0: ALL preprocessing in one launch -------------------------------
__global__ __launch_bounds__(256) void k_prep_all(
    const float* __restrict__ dcw, const float* __restrict__ w_off,
    const float* __restrict__ fp, const float* __restrict__ fn2,
    _Float16* __restrict__ wH, _Float16* __restrict__ BpT, _Float16* __restrict__ Bt,
    _Float16* __restrict__ featT) {
  const int bid = blockIdx.x;
  if (bid < 3375) {
    const int idx = bid * 256 + (int)threadIdx.x;
    if (idx < 73728) {            // wH[co][k*128+ci] = dcw[co][ci][k]
      const int co = idx / 1152;
      const int j  = idx - co * 1152;
      const int k  = j >> 7;
      const int ci = j & 127;
      wH[idx] = (_Float16)dcw[(co * 128 + ci) * 9 + k];
    } else if (idx < 73728 + 774144) {   // BpT[s][l4][n][8]
      const int j  = idx - 73728;
      const int c  = j & 7;
      const int n  = (j >> 3) % 448;
      const int sl = (j >> 3) / 448;
      const int l4 = sl & 3;
      const int s  = sl >> 2;
      const int t  = s / 6;
      const int cg = s - t * 6;
      const int ci = cg * 32 + l4 * 8 + c;
      BpT[j] = (_Float16)((n < COFF) ? w_off[((size_t)n * CIN_OFF + ci) * 9 + t] : 0.f);
    } else {                       // Bt[t][n][4] (tail ci 192..195)
      const int j = idx - 73728 - 774144;
      const int c = j & 3;
      const int n = (j >> 2) % 448;
      const int t = (j >> 2) / 448;
      Bt[j] = (_Float16)((n < COFF) ? w_off[((size_t)n * CIN_OFF + 192 + c) * 9 + t] : 0.f);
    }
  } else {
    const int t = (bid - 3375) * 256 + (int)threadIdx.x;  // 0..32767 = b*HW+hw
    const int b = t >> 14;
    const int hw = t & 16383;
#pragma unroll
    for (int g = 0; g < 16; ++g) {
      const float* src = (g < 8) ? fp : fn2;
      const int ch0 = (g & 7) * 8;
      half8 v;
#pragma unroll
      for (int c = 0; c < 8; ++c)
        v[c] = (_Float16)src[(size_t)(b * 64 + ch0 + c) * HW + hw];
      *(half8*)(featT + (((size_t)(b * 16 + g)) * HW + hw) * 8) = v;
    }
  }
}

// ---------------- kernel 1: FUSED offset-conv + deformable conv ---------------------------
// grid (128 h, 2 b), block 1024 (16 waves).
// Phase A: offconv MFMA (full-K LDS, round-11 structure: wm=wid&3, wn=wid>>2).
// Phase B: epilogue -> LDS so[128 px][456] fp16 (off 0..287, mask 288..431). NO global write.
// Phase C: deform PV: each thread gathers ITS OWN MFMA A-fragments (px=l15, tap k,
//          group g=cg*4+l4 -> 8ch bilinear sample) into registers; off/mask from so;
//          16 waves = 8 M-frags x 2 K-halves; partial-C reduced via LDS; coalesced store.
__global__ __launch_bounds__(1024, 4) void k_fused(
    const float* __restrict__ extra, const float* __restrict__ f1, const float* __restrict__ f2,
    const _Float16* __restrict__ BpT, const _Float16* __restrict__ Bt,
    const float* __restrict__ b_off,
    const _Float16* __restrict__ featT, const _Float16* __restrict__ wH,
    const float* __restrict__ dcb, float* __restrict__ out) {
  __shared__ __align__(16) _Float16 smA[3 * 130 * 192];  // 149,760 B (A tile -> so -> red)
  __shared__ __align__(16) _Float16 smT[3 * 130 * 4];
  const int h    = blockIdx.x;
  const int b    = blockIdx.y;
  const int tid  = (int)threadIdx.x;
  const int lane = tid & 63;
  const int wid  = tid >> 6;      // 0..15
  const int wm   = wid & 3;       // co-SIMD waves share M (LDS broadcast)
  const int wn   = wid >> 2;      // co-SIMD waves differ in N
  const int m_base = wm * 32;
  const int n_base = wn * 112;
  const int l15 = lane & 15;
  const int l4  = lane >> 4;

  // ---- zero px=0 / px=129 edge columns ----
  if (tid < 588) {
    const int p2 = tid % 98;
    const int rr = tid / 98;
    const int r  = (rr >= 3) ? (rr - 3) : rr;
    const int px = (rr >= 3) ? 129 : 0;
    if (p2 < 96) {
      const int ci = 2 * p2, biw = ci >> 3;
      const int sw = ((biw & 24) | ((biw & 7) ^ (px & 7))) << 3;
      *(half2v*)(smA + (r * 130 + px) * 192 + sw + (ci & 7)) = (half2v){(_Float16)0.f, (_Float16)0.f};
    } else {
      *(half2v*)(smT + (r * 130 + px) * 4 + 2 * (p2 - 96)) = (half2v){(_Float16)0.f, (_Float16)0.f};
    }
  }

  // ---- main staging: 3 r x 96 ci-pairs x 32 q ----
#pragma unroll 3
  for (int j = 0; j < 9; ++j) {
    const int J   = tid + 1024 * j;
    const int p2a = J & 15;
    const int qa  = (J >> 4) & 3;
    const int R   = J >> 6;
    const int r   = R / 48;
    const int rem = R - 48 * r;
    const int qh  = rem & 7;
    const int p2h = rem >> 3;
    const int q   = qa + 4 * qh;
    const int p2  = p2a + 16 * p2h;
    const int ci  = 2 * p2;
    const int gh  = h - 1 + r;
    float4 va = {0.f, 0.f, 0.f, 0.f}, vb = va;
    if ((unsigned)gh < (unsigned)Hh) {
      const float* xp = extra + (size_t)(b * 192 + ci) * HW + gh * Ww + 4 * q;
      va = *(const float4*)xp;
      vb = *(const float4*)(xp + HW);
    }
    const float av[4] = {va.x, va.y, va.z, va.w};
    const float bv[4] = {vb.x, vb.y, vb.z, vb.w};
    const int biw = p2 >> 2;
#pragma unroll
    for (int i = 0; i < 4; ++i) {
      const int px = 1 + 4 * q + i;
      const int sw = ((biw & 24) | ((biw & 7) ^ (px & 7))) << 3;
      half2v pk; pk[0] = (_Float16)av[i]; pk[1] = (_Float16)bv[i];
      *(half2v*)(smA + (r * 130 + px) * 192 + sw + (ci & 7)) = pk;
    }
  }
  // ---- tail staging: ci 192..195 ----
  if (tid < 192) {
    const int q   = tid & 31;
    const int p2t = (tid >> 5) & 1;
    const int r   = tid >> 6;
    const int gh  = h - 1 + r;
    float4 va = {0.f, 0.f, 0.f, 0.f}, vb = va;
    if ((unsigned)gh < (unsigned)Hh) {
      const float* xp = (p2t ? f2 : f1) + (size_t)(b * 2) * HW + gh * Ww + 4 * q;
      va = *(const float4*)xp;
      vb = *(const float4*)(xp + HW);
    }
    const float av[4] = {va.x, va.y, va.z, va.w};
    const float bv[4] = {vb.x, vb.y, vb.z, vb.w};
#pragma unroll
    for (int i = 0; i < 4; ++i) {
      const int px = 1 + 4 * q + i;
      half2v pk; pk[0] = (_Float16)av[i]; pk[1] = (_Float16)bv[i];
      *(half2v*)(smT + (r * 130 + px) * 4 + 2 * p2t) = pk;
    }
  }
  __syncthreads();

  // ---- Phase A K loop (round-11 structure) ----
  f32x4 acc[2][7];
#pragma unroll
  for (int i = 0; i < 2; ++i)
#pragma unroll
    for (int j = 0; j < 7; ++j) acc[i][j] = (f32x4){0.f, 0.f, 0.f, 0.f};

  const bool lz = (l4 == 0);
#pragma unroll 3
  for (int t = 0; t < 9; ++t) {
    const int ki = t / 3;
    const int kj = t - 3 * ki;
#pragma unroll
    for (int cg = 0; cg < 6; ++cg) {
      const int s4 = ((t * 6 + cg) * 4 + l4) * 448;
      half8 bf[7];
#pragma unroll
      for (int f = 0; f < 7; ++f)
        bf[f] = *(const half8*)(BpT + (size_t)(s4 + n_base + f * 16 + l15) * 8);
      half8 af[2];
#pragma unroll
      for (int mf = 0; mf < 2; ++mf) {
        const int px = m_base + mf * 16 + l15 + kj;
        const int bi = cg * 4 + l4;
        af[mf] = *(const half8*)(smA + (ki * 130 + px) * 192 +
                                 (((bi & 24) | ((bi & 7) ^ (px & 7))) << 3));
      }
#pragma unroll
      for (int mf = 0; mf < 2; ++mf)
#pragma unroll
        for (int f = 0; f < 7; ++f)
          acc[mf][f] = __builtin_amdgcn_mfma_f32_16x16x32_f16(af[mf], bf[f], acc[mf][f], 0, 0, 0);
    }
    half8 aft[2];
#pragma unroll
    for (int mf = 0; mf < 2; ++mf) {
      const int px = m_base + mf * 16 + l15 + kj;
      const half4 tv = *(const half4*)(smT + (ki * 130 + px) * 4);
      half8 a = {0, 0, 0, 0, 0, 0, 0, 0};
      if (lz) { a[0] = tv[0]; a[1] = tv[1]; a[2] = tv[2]; a[3] = tv[3]; }
      aft[mf] = a;
    }
#pragma unroll
    for (int f = 0; f < 7; ++f) {
      const half4 wv = *(const half4*)(Bt + (size_t)(t * 448 + n_base + f * 16 + l15) * 4);
      half8 bb = {0, 0, 0, 0, 0, 0, 0, 0};
      if (lz) { bb[0] = wv[0]; bb[1] = wv[1]; bb[2] = wv[2]; bb[3] = wv[3]; }
#pragma unroll
      for (int mf = 0; mf < 2; ++mf)
        acc[mf][f] = __builtin_amdgcn_mfma_f32_16x16x32_f16(aft[mf], bb, acc[mf][f], 0, 0, 0);
    }
  }

  // ---- Phase B: activation+flow -> so[128][456] fp16 in LDS (no global write) ----
  __syncthreads();
  _Float16* so = smA;
#pragma unroll
  for (int f = 0; f < 7; ++f) {
    const int n = n_base + f * 16 + l15;
    const float bias = (n < COFF) ? b_off[n] : 0.f;
    const bool isOff = (n < 288);
    const float* fl = (n < 144) ? f1 : f2;
    const size_t fladd = (size_t)(b * 2 + ((n & 1) ^ 1)) * HW + h * Ww;
#pragma unroll
    for (int mf = 0; mf < 2; ++mf) {
#pragma unroll
      for (int rr = 0; rr < 4; ++rr) {
        const int px = m_base + mf * 16 + l4 * 4 + rr;
        const float v = acc[mf][f][rr] + bias;
        float val;
        if (isOff) {
          const float e = __expf(2.f * v);
          val = 10.f * (1.f - 2.f / (e + 1.f)) + fl[fladd + px];
        } else {
          val = 1.f / (1.f + __expf(-v));
        }
        so[px * 456 + n] = (_Float16)val;
      }
    }
  }
  __syncthreads();

  // ---- Phase C: deform PV. wave = (mf8 = wid>>1, kh = wid&1); lane px=l15, g-lo=l4 ----
  const int kh  = wid & 1;
  const int mf8 = wid >> 1;           // 0..7 M-frag
  const int pxc = mf8 * 16 + l15;     // this lane's output pixel (A row)
  f32x4 pacc[4];
#pragma unroll
  for (int nf = 0; nf < 4; ++nf) pacc[nf] = (f32x4){0.f, 0.f, 0.f, 0.f};

#pragma unroll 3
  for (int j = 0; j < 18; ++j) {
    const int s  = kh * 18 + j;       // K32-step 0..35
    const int k  = s >> 2;            // tap 0..8
    const int cg = s & 3;
    const int g  = cg * 4 + l4;       // deform group 0..15
    const int r  = g * 9 + k;         // off/mask channel index
    const half2v od = *(const half2v*)(so + pxc * 456 + 2 * r);
    const float mk = (float)so[pxc * 456 + 288 + r];
    const int ki = (k >= 6) ? 2 : (k >= 3 ? 1 : 0);
    const int kj = k - 3 * ki;
    const float py = (float)(h - 1 + ki) + (float)od[0];
    const float px = (float)(pxc - 1 + kj) + (float)od[1];
    const float y0f = floorf(py), x0f = floorf(px);
    const int y0 = (int)y0f, x0 = (int)x0f;
    const float ly = py - y0f, lx = px - x0f;
    const float hy = 1.f - ly, hx = 1.f - lx;
    const int y1 = y0 + 1, x1 = x0 + 1;
    const bool vy0 = (unsigned)y0 < (unsigned)Hh, vy1 = (unsigned)y1 < (unsigned)Hh;
    const bool vx0 = (unsigned)x0 < (unsigned)Ww, vx1 = (unsigned)x1 < (unsigned)Ww;
    const float w00 = (vy0 && vx0) ? hy * hx : 0.f;
    const float w01 = (vy0 && vx1) ? hy * lx : 0.f;
    const float w10 = (vy1 && vx0) ? ly * hx : 0.f;
    const float w11 = (vy1 && vx1) ? ly * lx : 0.f;
    const int cy0 = min(max(y0, 0), Hh - 1), cy1 = min(max(y1, 0), Hh - 1);
    const int cx0 = min(max(x0, 0), Ww - 1), cx1 = min(max(x1, 0), Ww - 1);
    const _Float16* gbase = featT + ((size_t)(b * 16 + g) * HW) * 8;
    const half8 s00 = *(const half8*)(gbase + (cy0 * Ww + cx0) * 8);
    const half8 s01 = *(const half8*)(gbase + (cy0 * Ww + cx1) * 8);
    const half8 s10 = *(const half8*)(gbase + (cy1 * Ww + cx0) * 8);
    const half8 s11 = *(const half8*)(gbase + (cy1 * Ww + cx1) * 8);
    half8 af = s00 * splat8(w00) + s01 * splat8(w01) + s10 * splat8(w10) + s11 * splat8(w11);
    af = af * splat8(mk);
    const int koff = s * 32 + l4 * 8;
#pragma unroll
    for (int nf = 0; nf < 4; ++nf) {
      const half8 bf = *(const half8*)(wH + (size_t)(nf * 16 + l15) * 1152 + koff);
      pacc[nf] = __builtin_amdgcn_mfma_f32_16x16x32_f16(af, bf, pacc[nf], 0, 0, 0);
    }
  }
  __syncthreads();                    // so no longer needed; reuse smA as red
  float* red = (float*)smA;           // red[256 rows][66]
#pragma unroll
  for (int nf = 0; nf < 4; ++nf)
#pragma unroll
    for (int rr = 0; rr < 4; ++rr)
      red[(wid * 16 + l4 * 4 + rr) * 66 + nf * 16 + l15] = pacc[nf][rr];
  __syncthreads();

  // reduce K-halves + bias, coalesced store: out[b][n][h][px]
  for (int T = tid; T < 8192; T += 1024) {
    const int px2 = T & 127;
    const int n   = T >> 7;
    const int mfr = px2 >> 4;
    const int pxl = px2 & 15;
    const float val = red[((mfr * 2 + 0) * 16 + pxl) * 66 + n] +
                      red[((mfr * 2 + 1) * 16 + pxl) * 66 + n];
    out[(size_t)(b * 64 + n) * HW + h * Ww + px2] = val + dcb[n];
  }
}

extern "C" void kernel_launch(void* const* d_in, const int* in_sizes, int n_in,
                              void* d_out, int out_size, void* d_ws, size_t ws_size,
                              hipStream_t stream) {
  const float* extra = (const float*)d_in[0];
  const float* f1    = (const float*)d_in[1];
  const float* f2    = (const float*)d_in[2];
  const float* fp    = (const float*)d_in[3];
  const float* fn2   = (const float*)d_in[4];
  const float* w_off = (const float*)d_in[5];
  const float* b_off = (const float*)d_in[6];
  const float* dcw   = (const float*)d_in[7];
  const float* dcb   = (const float*)d_in[8];
  float* out = (float*)d_out;

  // ws layout (~10 MB): off/mask buffers eliminated by fusion
  _Float16* featT = (_Float16*)d_ws;                     // 2*16*HW*8 fp16 = 8.4 MB
  _Float16* BpT   = featT + (size_t)2 * 128 * HW;        // 774144 fp16
  _Float16* Bt    = BpT + 774144;                        // 16128 fp16
  _Float16* wH    = Bt + 16128;                          // 73728 fp16

  hipLaunchKernelGGL(k_prep_all, dim3(3503), dim3(256), 0, stream,
                     dcw, w_off, fp, fn2, wH, BpT, Bt, featT);
  hipLaunchKernelGGL(k_fused, dim3(128, 2), dim3(1024), 0, stream,
                     extra, f1, f2, BpT, Bt, b_off, featT, wH, dcb, out);
}

// Round 15
// 185.076 us; speedup vs baseline: 1.0167x; 1.0167x over previous
//
#include <hip/hip_runtime.h>
#include <math.h>

#define Hh 128
#define Ww 128
#define HW (128*128)
#define CIN_OFF 196
#define COFF 432

typedef _Float16 half8 __attribute__((ext_vector_type(8)));
typedef _Float16 half4 __attribute__((ext_vector_type(4)));
typedef _Float16 half2v __attribute__((ext_vector_type(2)));
typedef float f32x4 __attribute__((ext_vector_type(4)));

static __device__ __forceinline__ half8 splat8(float v) {
  _Float16 h = (_Float16)v;
  half8 r = {h, h, h, h, h, h, h, h};
  return r;
}

// ---------------- kernel 0: ALL preprocessing in one launch -------------------------------
__global__ __launch_bounds__(256) void k_prep_all(
    const float* __restrict__ dcw, const float* __restrict__ w_off,
    const float* __restrict__ fp, const float* __restrict__ fn2,
    _Float16* __restrict__ wH, _Float16* __restrict__ BpT, _Float16* __restrict__ Bt,
    _Float16* __restrict__ featT) {
  const int bid = blockIdx.x;
  if (bid < 3375) {
    const int idx = bid * 256 + (int)threadIdx.x;
    if (idx < 73728) {            // wH[co][k*128+ci] = dcw[co][ci][k]
      const int co = idx / 1152;
      const int j  = idx - co * 1152;
      const int k  = j >> 7;
      const int ci = j & 127;
      wH[idx] = (_Float16)dcw[(co * 128 + ci) * 9 + k];
    } else if (idx < 73728 + 774144) {   // BpT[s][l4][n][8]
      const int j  = idx - 73728;
      const int c  = j & 7;
      const int n  = (j >> 3) % 448;
      const int sl = (j >> 3) / 448;
      const int l4 = sl & 3;
      const int s  = sl >> 2;
      const int t  = s / 6;
      const int cg = s - t * 6;
      const int ci = cg * 32 + l4 * 8 + c;
      BpT[j] = (_Float16)((n < COFF) ? w_off[((size_t)n * CIN_OFF + ci) * 9 + t] : 0.f);
    } else {                       // Bt[t][n][4] (tail ci 192..195)
      const int j = idx - 73728 - 774144;
      const int c = j & 3;
      const int n = (j >> 2) % 448;
      const int t = (j >> 2) / 448;
      Bt[j] = (_Float16)((n < COFF) ? w_off[((size_t)n * CIN_OFF + 192 + c) * 9 + t] : 0.f);
    }
  } else {
    const int t = (bid - 3375) * 256 + (int)threadIdx.x;  // 0..32767 = b*HW+hw
    const int b = t >> 14;
    const int hw = t & 16383;
#pragma unroll
    for (int g = 0; g < 16; ++g) {
      const float* src = (g < 8) ? fp : fn2;
      const int ch0 = (g & 7) * 8;
      half8 v;
#pragma unroll
      for (int c = 0; c < 8; ++c)
        v[c] = (_Float16)src[(size_t)(b * 64 + ch0 + c) * HW + hw];
      *(half8*)(featT + (((size_t)(b * 16 + g)) * HW + hw) * 8) = v;
    }
  }
}

// ---------------- kernel 1: offset conv, FULL-K LDS, 8 waves, M_wave=64 -------------------
// grid (128 h, 2 b), block 512 (8 waves: 2M x 4N). Per wave: 64 px x 112 n.
// B-reads are L1-access-throughput bound; traffic scales as total_M / M_wave.
// M_wave 32->64 halves per-CU L1-B-traffic (7 B-loads feed 28 MFMAs).
// (Round-14 NaN fix: edge zeroing is now a grid-stride loop, not `if (tid<588)` —
//  588 tasks > 512 threads left px=129/r=2 uninitialized.)
__global__ __launch_bounds__(512, 2) void k_offconv_mfma(
    const float* __restrict__ extra, const float* __restrict__ f1, const float* __restrict__ f2,
    const _Float16* __restrict__ BpT, const _Float16* __restrict__ Bt,
    const float* __restrict__ b_off,
    _Float16* __restrict__ off_pm, _Float16* __restrict__ mask_pm) {
  __shared__ __align__(16) _Float16 smA[3 * 130 * 192];  // 149,760 B (reused by epilogue)
  __shared__ __align__(16) _Float16 smT[3 * 130 * 4];    //   3,120 B
  const int h    = blockIdx.x;
  const int b    = blockIdx.y;
  const int tid  = (int)threadIdx.x;
  const int lane = tid & 63;
  const int wid  = tid >> 6;          // 0..7
  const int wm   = wid & 1;           // co-SIMD pair shares M (LDS broadcast)
  const int wn   = (wid >> 1) & 3;    // co-SIMD pair differs in N
  const int m_base = wm * 64;
  const int n_base = wn * 112;
  const int l15 = lane & 15;
  const int l4  = lane >> 4;

  // ---- zero px=0 / px=129 edge columns (grid-stride: 588 tasks, any block size) ----
  for (int z = tid; z < 588; z += 512) {
    const int p2 = z % 98;
    const int rr = z / 98;
    const int r  = (rr >= 3) ? (rr - 3) : rr;
    const int px = (rr >= 3) ? 129 : 0;
    if (p2 < 96) {
      const int ci = 2 * p2, biw = ci >> 3;
      const int sw = ((biw & 24) | ((biw & 7) ^ (px & 7))) << 3;
      *(half2v*)(smA + (r * 130 + px) * 192 + sw + (ci & 7)) = (half2v){(_Float16)0.f, (_Float16)0.f};
    } else {
      *(half2v*)(smT + (r * 130 + px) * 4 + 2 * (p2 - 96)) = (half2v){(_Float16)0.f, (_Float16)0.f};
    }
  }

  // ---- main staging: 3 r x 96 ci-pairs x 32 q = 9216 tasks = 18 x 512 ----
#pragma unroll 3
  for (int j = 0; j < 18; ++j) {
    const int J   = tid + 512 * j;
    const int p2a = J & 15;
    const int qa  = (J >> 4) & 3;
    const int R   = J >> 6;                  // wave-uniform (0..143)
    const int r   = R / 48;
    const int rem = R - 48 * r;
    const int qh  = rem & 7;
    const int p2h = rem >> 3;                // 0..5
    const int q   = qa + 4 * qh;             // 0..31
    const int p2  = p2a + 16 * p2h;          // 0..95
    const int ci  = 2 * p2;
    const int gh  = h - 1 + r;
    float4 va = {0.f, 0.f, 0.f, 0.f}, vb = va;
    if ((unsigned)gh < (unsigned)Hh) {
      const float* xp = extra + (size_t)(b * 192 + ci) * HW + gh * Ww + 4 * q;
      va = *(const float4*)xp;
      vb = *(const float4*)(xp + HW);
    }
    const float av[4] = {va.x, va.y, va.z, va.w};
    const float bv[4] = {vb.x, vb.y, vb.z, vb.w};
    const int biw = p2 >> 2;
#pragma unroll
    for (int i = 0; i < 4; ++i) {
      const int px = 1 + 4 * q + i;
      const int sw = ((biw & 24) | ((biw & 7) ^ (px & 7))) << 3;
      half2v pk; pk[0] = (_Float16)av[i]; pk[1] = (_Float16)bv[i];
      *(half2v*)(smA + (r * 130 + px) * 192 + sw + (ci & 7)) = pk;
    }
  }
  // ---- tail staging: ci 192..195 (f1, f2) ----
  if (tid < 192) {
    const int q   = tid & 31;
    const int p2t = (tid >> 5) & 1;
    const int r   = tid >> 6;
    const int gh  = h - 1 + r;
    float4 va = {0.f, 0.f, 0.f, 0.f}, vb = va;
    if ((unsigned)gh < (unsigned)Hh) {
      const float* xp = (p2t ? f2 : f1) + (size_t)(b * 2) * HW + gh * Ww + 4 * q;
      va = *(const float4*)xp;
      vb = *(const float4*)(xp + HW);
    }
    const float av[4] = {va.x, va.y, va.z, va.w};
    const float bv[4] = {vb.x, vb.y, vb.z, vb.w};
#pragma unroll
    for (int i = 0; i < 4; ++i) {
      const int px = 1 + 4 * q + i;
      half2v pk; pk[0] = (_Float16)av[i]; pk[1] = (_Float16)bv[i];
      *(half2v*)(smT + (r * 130 + px) * 4 + 2 * p2t) = pk;
    }
  }
  __syncthreads();

  // ---- barrier-free K loop: 9 taps x (6 x K32 + K16-tail), 28 MFMA per step ----
  f32x4 acc[4][7];
#pragma unroll
  for (int i = 0; i < 4; ++i)
#pragma unroll
    for (int j = 0; j < 7; ++j) acc[i][j] = (f32x4){0.f, 0.f, 0.f, 0.f};

  const bool lz = (l4 == 0);
#pragma unroll 3
  for (int t = 0; t < 9; ++t) {
    const int ki = t / 3;
    const int kj = t - 3 * ki;
#pragma unroll
    for (int cg = 0; cg < 6; ++cg) {
      const int s4 = ((t * 6 + cg) * 4 + l4) * 448;
      half8 bf[7];
#pragma unroll
      for (int f = 0; f < 7; ++f)
        bf[f] = *(const half8*)(BpT + (size_t)(s4 + n_base + f * 16 + l15) * 8);
      half8 af[4];
#pragma unroll
      for (int mf = 0; mf < 4; ++mf) {
        const int px = m_base + mf * 16 + l15 + kj;
        const int bi = cg * 4 + l4;
        af[mf] = *(const half8*)(smA + (ki * 130 + px) * 192 +
                                 (((bi & 24) | ((bi & 7) ^ (px & 7))) << 3));
      }
#pragma unroll
      for (int mf = 0; mf < 4; ++mf)
#pragma unroll
        for (int f = 0; f < 7; ++f)
          acc[mf][f] = __builtin_amdgcn_mfma_f32_16x16x32_f16(af[mf], bf[f], acc[mf][f], 0, 0, 0);
    }
    // tail: ci 192..195 as a l4==0-masked K32 MFMA
    half8 aft[4];
#pragma unroll
    for (int mf = 0; mf < 4; ++mf) {
      const int px = m_base + mf * 16 + l15 + kj;
      const half4 tv = *(const half4*)(smT + (ki * 130 + px) * 4);
      half8 a = {0, 0, 0, 0, 0, 0, 0, 0};
      if (lz) { a[0] = tv[0]; a[1] = tv[1]; a[2] = tv[2]; a[3] = tv[3]; }
      aft[mf] = a;
    }
#pragma unroll
    for (int f = 0; f < 7; ++f) {
      const half4 wv = *(const half4*)(Bt + (size_t)(t * 448 + n_base + f * 16 + l15) * 4);
      half8 bb = {0, 0, 0, 0, 0, 0, 0, 0};
      if (lz) { bb[0] = wv[0]; bb[1] = wv[1]; bb[2] = wv[2]; bb[3] = wv[3]; }
#pragma unroll
      for (int mf = 0; mf < 4; ++mf)
        acc[mf][f] = __builtin_amdgcn_mfma_f32_16x16x32_f16(aft[mf], bb, acc[mf][f], 0, 0, 0);
    }
  }

  // ---- epilogue: activation+flow -> LDS so[128][456] fp16 -> coalesced stores ----
  __syncthreads();
  _Float16* so = smA;
  const int hw0 = h * Ww;
#pragma unroll
  for (int f = 0; f < 7; ++f) {
    const int n = n_base + f * 16 + l15;
    const float bias = (n < COFF) ? b_off[n] : 0.f;
    const bool isOff = (n < 288);
    const float* fl = (n < 144) ? f1 : f2;
    const size_t fladd = (size_t)(b * 2 + ((n & 1) ^ 1)) * HW + hw0;
#pragma unroll
    for (int mf = 0; mf < 4; ++mf) {
#pragma unroll
      for (int rr = 0; rr < 4; ++rr) {
        const int px = m_base + mf * 16 + l4 * 4 + rr;
        const float v = acc[mf][f][rr] + bias;
        float val;
        if (isOff) {
          const float e = __expf(2.f * v);
          val = 10.f * (1.f - 2.f / (e + 1.f)) + fl[fladd + px];
        } else {
          val = 1.f / (1.f + __expf(-v));
        }
        so[px * 456 + n] = (_Float16)val;
      }
    }
  }
  __syncthreads();
  for (int T = tid; T < 4608; T += 512) {
    const int px = T / 36, c = T - px * 36;
    const half8 v = *(const half8*)(so + px * 456 + c * 8);
    *(half8*)(off_pm + ((size_t)b * HW + hw0 + px) * 288 + c * 8) = v;
  }
  for (int T = tid; T < 2304; T += 512) {
    const int px = T / 18, c = T - px * 18;
    const half8 v = *(const half8*)(so + px * 456 + 288 + c * 8);
    *(half8*)(mask_pm + ((size_t)b * HW + hw0 + px) * 144 + c * 8) = v;
  }
}

// ---------------- kernel 2: modulated deformable conv, 16 px/block, MFMA phase 2 ----------
__global__ __launch_bounds__(256, 4) void k_deform2(
    const _Float16* __restrict__ featT, const _Float16* __restrict__ off_pm,
    const _Float16* __restrict__ mask_pm, const _Float16* __restrict__ wH,
    const float* __restrict__ dcb, float* __restrict__ out) {
  __shared__ __align__(16) char smem[16 * 1160 * 2];   // 37120 B
  _Float16* sm = (_Float16*)smem;
  float* red = (float*)smem;
  const int w0  = blockIdx.x * 16;
  const int h   = blockIdx.y;
  const int b   = blockIdx.z;
  const int tid = (int)threadIdx.x;
  const int lane = tid & 63, wid = tid >> 6;
  const int l15 = lane & 15, l4 = lane >> 4;

  // phase 0: issue all off/mask loads
  half2v offv[9];
  _Float16 mkv[9];
#pragma unroll
  for (int i = 0; i < 9; ++i) {
    const int p   = tid + i * 256;
    const int pix = p / 144;
    const int r   = p - pix * 144;
    const int w   = w0 + pix;
    const int hw  = h * Ww + w;
    offv[i] = *(const half2v*)(off_pm + ((size_t)b * HW + hw) * 288 + 2 * r);
    mkv[i]  = mask_pm[((size_t)b * HW + hw) * 144 + r];
  }
  // phase 1: bilinear gathers (fully unrolled -> feat loads overlap)
#pragma unroll
  for (int i = 0; i < 9; ++i) {
    const int p   = tid + i * 256;
    const int pix = p / 144;
    const int r   = p - pix * 144;
    const int g   = r / 9;
    const int k   = r - g * 9;
    const int w   = w0 + pix;
    const float mk = (float)mkv[i];
    const int ki = (k >= 6) ? 2 : (k >= 3 ? 1 : 0);
    const int kj = k - 3 * ki;
    const float py = (float)(h - 1 + ki) + (float)offv[i][0];
    const float px = (float)(w - 1 + kj) + (float)offv[i][1];
    const float y0f = floorf(py), x0f = floorf(px);
    const int y0 = (int)y0f, x0 = (int)x0f;
    const float ly = py - y0f, lx = px - x0f;
    const float hy = 1.f - ly, hx = 1.f - lx;
    const int y1 = y0 + 1, x1 = x0 + 1;
    const bool vy0 = (unsigned)y0 < (unsigned)Hh, vy1 = (unsigned)y1 < (unsigned)Hh;
    const bool vx0 = (unsigned)x0 < (unsigned)Ww, vx1 = (unsigned)x1 < (unsigned)Ww;
    const float w00 = (vy0 && vx0) ? hy * hx : 0.f;
    const float w01 = (vy0 && vx1) ? hy * lx : 0.f;
    const float w10 = (vy1 && vx0) ? ly * hx : 0.f;
    const float w11 = (vy1 && vx1) ? ly * lx : 0.f;
    const int cy0 = min(max(y0, 0), Hh - 1), cy1 = min(max(y1, 0), Hh - 1);
    const int cx0 = min(max(x0, 0), Ww - 1), cx1 = min(max(x1, 0), Ww - 1);
    const _Float16* gbase = featT + ((size_t)(b * 16 + g) * HW) * 8;
    const half8 s00 = *(const half8*)(gbase + (cy0 * Ww + cx0) * 8);
    const half8 s01 = *(const half8*)(gbase + (cy0 * Ww + cx1) * 8);
    const half8 s10 = *(const half8*)(gbase + (cy1 * Ww + cx0) * 8);
    const half8 s11 = *(const half8*)(gbase + (cy1 * Ww + cx1) * 8);
    half8 v = s00 * splat8(w00) + s01 * splat8(w01) + s10 * splat8(w10) + s11 * splat8(w11);
    v = v * splat8(mk);
    const int swz = (g ^ (k & 7)) << 3;
    *(half8*)(sm + pix * 1160 + k * 128 + swz) = v;
  }
  __syncthreads();

  f32x4 acc[4];
#pragma unroll
  for (int nf = 0; nf < 4; ++nf) acc[nf] = (f32x4){0.f, 0.f, 0.f, 0.f};
#pragma unroll
  for (int j = 0; j < 9; ++j) {
    const int s  = wid * 9 + j;
    const int k  = s >> 2;
    const int cg = s & 3;
    const int gidx = cg * 4 + l4;
    const half8 af = *(const half8*)(sm + l15 * 1160 + k * 128 + ((gidx ^ (k & 7)) << 3));
    const int koff = s * 32 + l4 * 8;
#pragma unroll
    for (int nf = 0; nf < 4; ++nf) {
      const half8 bf = *(const half8*)(wH + (nf * 16 + l15) * 1152 + koff);
      acc[nf] = __builtin_amdgcn_mfma_f32_16x16x32_f16(af, bf, acc[nf], 0, 0, 0);
    }
  }
  __syncthreads();
#pragma unroll
  for (int nf = 0; nf < 4; ++nf)
#pragma unroll
    for (int rr = 0; rr < 4; ++rr)
      red[(wid * 16 + l4 * 4 + rr) * 66 + nf * 16 + l15] = acc[nf][rr];
  __syncthreads();

  const int m  = tid & 15;
  const int ng = tid >> 4;
#pragma unroll
  for (int i = 0; i < 4; ++i) {
    const int n = ng + 16 * i;
    float val = red[(0 * 16 + m) * 66 + n] + red[(1 * 16 + m) * 66 + n] +
                red[(2 * 16 + m) * 66 + n] + red[(3 * 16 + m) * 66 + n];
    out[(size_t)(b * 64 + n) * HW + h * Ww + w0 + m] = val + dcb[n];
  }
}

extern "C" void kernel_launch(void* const* d_in, const int* in_sizes, int n_in,
                              void* d_out, int out_size, void* d_ws, size_t ws_size,
                              hipStream_t stream) {
  const float* extra = (const float*)d_in[0];
  const float* f1    = (const float*)d_in[1];
  const float* f2    = (const float*)d_in[2];
  const float* fp    = (const float*)d_in[3];
  const float* fn2   = (const float*)d_in[4];
  const float* w_off = (const float*)d_in[5];
  const float* b_off = (const float*)d_in[6];
  const float* dcw   = (const float*)d_in[7];
  const float* dcb   = (const float*)d_in[8];
  float* out = (float*)d_out;

  // ws layout (~40 MB)
  _Float16* off_pm  = (_Float16*)d_ws;                   // 2*HW*288 fp16 = 18.9 MB
  _Float16* mask_pm = off_pm + (size_t)2 * 288 * HW;     // 2*HW*144 fp16 = 9.4 MB
  _Float16* featT   = mask_pm + (size_t)2 * 144 * HW;    // 2*16*HW*8 fp16 = 8.4 MB
  _Float16* BpT     = featT + (size_t)2 * 128 * HW;      // 774144 fp16
  _Float16* Bt      = BpT + 774144;                      // 16128 fp16
  _Float16* wH      = Bt + 16128;                        // 73728 fp16

  hipLaunchKernelGGL(k_prep_all, dim3(3503), dim3(256), 0, stream,
                     dcw, w_off, fp, fn2, wH, BpT, Bt, featT);
  hipLaunchKernelGGL(k_offconv_mfma, dim3(128, 2), dim3(512), 0, stream,
                     extra, f1, f2, BpT, Bt, b_off, off_pm, mask_pm);
  hipLaunchKernelGGL(k_deform2, dim3(8, 128, 2), dim3(256), 0, stream,
                     featT, off_pm, mask_pm, wH, dcb, out);
}

// Round 16
// 185.064 us; speedup vs baseline: 1.0168x; 1.0001x over previous
//
#include <hip/hip_runtime.h>
#include <math.h>

#define Hh 128
#define Ww 128
#define HW (128*128)
#define CIN_OFF 196
#define COFF 432

typedef _Float16 half8 __attribute__((ext_vector_type(8)));
typedef _Float16 half2v __attribute__((ext_vector_type(2)));
typedef float f32x4 __attribute__((ext_vector_type(4)));

static __device__ __forceinline__ half8 splat8(float v) {
  _Float16 h = (_Float16)v;
  half8 r = {h, h, h, h, h, h, h, h};
  return r;
}

// ---------------- kernel 0: ALL preprocessing in one launch -------------------------------
// BpT2: 63 K32-slices of [l4:4][n':448][c:8] fp16, slice = t*7+jj.
//   jj<6: ci = jj*32+l4*8+c (0..191); jj==6: ci = 192+c if (l4==0 && c<4) else ZERO (tail pad).
//   stored n' = n ^ ((l4&1)<<2)  (bank spread; kernel reads with same XOR).
__global__ __launch_bounds__(256) void k_prep_all(
    const float* __restrict__ dcw, const float* __restrict__ w_off,
    const float* __restrict__ fp, const float* __restrict__ fn2,
    _Float16* __restrict__ wH, _Float16* __restrict__ BpT2,
    _Float16* __restrict__ featT) {
  const int bid = blockIdx.x;
  if (bid < 3816) {
    const int idx = bid * 256 + (int)threadIdx.x;
    if (idx < 73728) {            // wH[co][k*128+ci] = dcw[co][ci][k]
      const int co = idx / 1152;
      const int j  = idx - co * 1152;
      const int k  = j >> 7;
      const int ci = j & 127;
      wH[idx] = (_Float16)dcw[(co * 128 + ci) * 9 + k];
    } else {                      // BpT2 (903168 halves)
      const int j  = idx - 73728;
      const int c  = j & 7;
      const int m  = (j >> 3) % 448;       // stored n'
      const int sl = (j >> 3) / 448;       // 0..251
      const int l4 = sl & 3;
      const int u  = sl >> 2;              // slice 0..62
      const int t  = u / 7;
      const int jj = u - t * 7;
      const int n  = m ^ ((l4 & 1) << 2);  // logical n
      float v = 0.f;
      if (n < COFF) {
        if (jj < 6) {
          const int ci = jj * 32 + l4 * 8 + c;     // 0..191
          v = w_off[((size_t)n * CIN_OFF + ci) * 9 + t];
        } else if (l4 == 0 && c < 4) {
          v = w_off[((size_t)n * CIN_OFF + 192 + c) * 9 + t];
        }
      }
      BpT2[j] = (_Float16)v;
    }
  } else {
    const int t = (bid - 3816) * 256 + (int)threadIdx.x;  // 0..32767 = b*HW+hw
    const int b = t >> 14;
    const int hw = t & 16383;
#pragma unroll
    for (int g = 0; g < 16; ++g) {
      const float* src = (g < 8) ? fp : fn2;
      const int ch0 = (g & 7) * 8;
      half8 v;
#pragma unroll
      for (int c = 0; c < 8; ++c)
        v[c] = (_Float16)src[(size_t)(b * 64 + ch0 + c) * HW + hw];
      *(half8*)(featT + (((size_t)(b * 16 + g)) * HW + hw) * 8) = v;
    }
  }
}

// ---------------- kernel 1: offset conv, A in LDS (2 ci-halves) + B streamed through LDS --
// grid (128 h, 2 b), block 512 (8 waves: 2M x 4N, M_wave=64).
// 63 K32-steps; per step: issue next B slice loads (regs) -> compute (B from LDS dbuf)
// -> write regs to alternate buffer -> barrier.  (T14 async-split; B slice = 28,672B.)
__global__ __launch_bounds__(512, 2) void k_offconv_mfma(
    const float* __restrict__ extra, const float* __restrict__ f1, const float* __restrict__ f2,
    const _Float16* __restrict__ BpT2, const float* __restrict__ b_off,
    _Float16* __restrict__ off_pm, _Float16* __restrict__ mask_pm) {
  __shared__ __align__(16) char LDSBUF[157184];
  _Float16* smA = (_Float16*)LDSBUF;               // [3][130][128] halves = 99,840 B
  _Float16* smB = (_Float16*)(LDSBUF + 99840);     // 2 x 14336 halves = 57,344 B
  const int h    = blockIdx.x;
  const int b    = blockIdx.y;
  const int tid  = (int)threadIdx.x;
  const int lane = tid & 63;
  const int wid  = tid >> 6;          // 0..7
  const int wm   = wid & 1;
  const int wn   = (wid >> 1) & 3;
  const int m_base = wm * 64;
  const int n_base = wn * 112;
  const int l15 = lane & 15;
  const int l4  = lane >> 4;
  const int xr  = (l4 & 1) << 2;      // B n-XOR (matches prep layout)

  // ---- zero px=0 / px=129 edge rows (full 128-wide, stays valid across both halves) ----
  if (tid < 384) {                    // 3 r x 2 px x 64 half2
    const int pair = tid & 63;
    const int rp   = tid >> 6;        // 0..5
    const int r    = rp >> 1;
    const int px   = (rp & 1) ? 129 : 0;
    *(half2v*)(smA + (r * 130 + px) * 128 + pair * 2) =
        (half2v){(_Float16)0.f, (_Float16)0.f};
  }

  // ---- A staging, half 0: ci 0..127 (all extra), 12 x 512 tasks ----
#pragma unroll 2
  for (int it = 0; it < 12; ++it) {
    const int J   = tid + 512 * it;
    const int p2a = J & 15;
    const int qa  = (J >> 4) & 3;
    const int R   = J >> 6;           // 0..95
    const int r   = R >> 5;
    const int rem = R & 31;
    const int qh  = rem & 7;
    const int p2h = rem >> 3;         // 0..3
    const int q   = qa + 4 * qh;
    const int p2  = p2a + 16 * p2h;   // 0..63
    const int cil = 2 * p2;           // 0..126
    const int gh  = h - 1 + r;
    float4 va = {0.f, 0.f, 0.f, 0.f}, vb = va;
    if ((unsigned)gh < (unsigned)Hh) {
      const float* xp = extra + (size_t)(b * 192 + cil) * HW + gh * Ww + 4 * q;
      va = *(const float4*)xp;
      vb = *(const float4*)(xp + HW);
    }
    const float av[4] = {va.x, va.y, va.z, va.w};
    const float bv[4] = {vb.x, vb.y, vb.z, vb.w};
    const int bi = p2 >> 2;
#pragma unroll
    for (int i = 0; i < 4; ++i) {
      const int px = 1 + 4 * q + i;
      const int sw = (bi & 8) | ((bi & 7) ^ (px & 7));
      half2v pk; pk[0] = (_Float16)av[i]; pk[1] = (_Float16)bv[i];
      *(half2v*)(smA + (r * 130 + px) * 128 + sw * 8 + (cil & 7)) = pk;
    }
  }

  // ---- prologue B stage: slice 0 -> buf 0 ----
  half8 breg0, breg1, breg2, breg3;
  {
    const _Float16* src = BpT2 + tid * 8;
    breg0 = *(const half8*)src;
    breg1 = *(const half8*)(src + 4096);
    breg2 = *(const half8*)(src + 8192);
    if (tid < 256) breg3 = *(const half8*)(src + 12288);
    _Float16* dst = smB + tid * 8;
    *(half8*)dst = breg0;
    *(half8*)(dst + 4096) = breg1;
    *(half8*)(dst + 8192) = breg2;
    if (tid < 256) *(half8*)(dst + 12288) = breg3;
  }
  __syncthreads();

  // ---- K loop: 63 steps, 2-phase pipelined B, single barrier per step ----
  f32x4 acc[4][7];
#pragma unroll
  for (int i = 0; i < 4; ++i)
#pragma unroll
    for (int j = 0; j < 7; ++j) acc[i][j] = (f32x4){0.f, 0.f, 0.f, 0.f};

  int u = 0;
#pragma unroll 1
  for (int hf = 0; hf < 2; ++hf) {
    if (hf == 1) {
      // ---- A restage, half 1: ci 128..223 (extra 128..191, f1/f2 192..195, zero pad) ----
#pragma unroll 2
      for (int it = 0; it < 9; ++it) {
        const int J   = tid + 512 * it;
        const int p2a = J & 15;
        const int qa  = (J >> 4) & 3;
        const int R   = J >> 6;         // 0..71
        const int r   = R / 24;
        const int rem = R - 24 * r;
        const int qh  = rem & 7;
        const int p2h = rem >> 3;       // 0..2
        const int q   = qa + 4 * qh;
        const int p2  = p2a + 16 * p2h; // 0..47
        const int cil = 2 * p2;         // 0..94
        const int gh  = h - 1 + r;
        float4 va = {0.f, 0.f, 0.f, 0.f}, vb = va;
        if ((unsigned)gh < (unsigned)Hh && p2 < 34) {
          const float* xp;
          if (p2 < 32)      xp = extra + (size_t)(b * 192 + 128 + cil) * HW;
          else if (p2 == 32) xp = f1 + (size_t)(b * 2) * HW;
          else               xp = f2 + (size_t)(b * 2) * HW;
          va = *(const float4*)(xp + gh * Ww + 4 * q);
          vb = *(const float4*)(xp + HW + gh * Ww + 4 * q);
        }
        const float av[4] = {va.x, va.y, va.z, va.w};
        const float bv[4] = {vb.x, vb.y, vb.z, vb.w};
        const int bi = p2 >> 2;
#pragma unroll
        for (int i = 0; i < 4; ++i) {
          const int px = 1 + 4 * q + i;
          const int sw = (bi & 8) | ((bi & 7) ^ (px & 7));
          half2v pk; pk[0] = (_Float16)av[i]; pk[1] = (_Float16)bv[i];
          *(half2v*)(smA + (r * 130 + px) * 128 + sw * 8 + (cil & 7)) = pk;
        }
      }
      __syncthreads();
    }
    const int JL = hf ? 3 : 4;
#pragma unroll 1
    for (int t = 0; t < 9; ++t) {
      const int ki = t / 3;
      const int kj = t - 3 * ki;
#pragma unroll 1
      for (int jl = 0; jl < JL; ++jl) {
        const int un = u + 1;
        const bool pf = (un < 63);
        if (pf) {  // issue next slice's loads (L2-hot) before compute
          const int su = (un < 36) ? ((un >> 2) * 7 + (un & 3))
                                   : (((un - 36) / 3) * 7 + 4 + (un - 36) % 3);
          const _Float16* src = BpT2 + (size_t)su * 14336 + tid * 8;
          breg0 = *(const half8*)src;
          breg1 = *(const half8*)(src + 4096);
          breg2 = *(const half8*)(src + 8192);
          if (tid < 256) breg3 = *(const half8*)(src + 12288);
        }
        // compute step u from smB buf (u&1) and smA
        const _Float16* bb = smB + (u & 1) * 14336;
        half8 bf[7];
#pragma unroll
        for (int f = 0; f < 7; ++f) {
          const int nn = n_base + f * 16 + l15;
          bf[f] = *(const half8*)(bb + (l4 * 448 + (nn ^ xr)) * 8);
        }
        const int bi = jl * 4 + l4;
        half8 af[4];
#pragma unroll
        for (int mf = 0; mf < 4; ++mf) {
          const int px = m_base + mf * 16 + l15 + kj;
          af[mf] = *(const half8*)(smA + (ki * 130 + px) * 128 +
                                   (((bi & 8) | ((bi & 7) ^ (px & 7))) << 3));
        }
#pragma unroll
        for (int mf = 0; mf < 4; ++mf)
#pragma unroll
          for (int f = 0; f < 7; ++f)
            acc[mf][f] = __builtin_amdgcn_mfma_f32_16x16x32_f16(af[mf], bf[f], acc[mf][f], 0, 0, 0);
        if (pf) {  // write next slice into alternate buffer
          _Float16* dst = smB + (un & 1) * 14336 + tid * 8;
          *(half8*)dst = breg0;
          *(half8*)(dst + 4096) = breg1;
          *(half8*)(dst + 8192) = breg2;
          if (tid < 256) *(half8*)(dst + 12288) = breg3;
        }
        __syncthreads();
        ++u;
      }
    }
  }

  // ---- epilogue: activation+flow -> LDS so[128][456] fp16 -> coalesced stores ----
  _Float16* so = (_Float16*)LDSBUF;
  const int hw0 = h * Ww;
#pragma unroll
  for (int f = 0; f < 7; ++f) {
    const int n = n_base + f * 16 + l15;
    const float bias = (n < COFF) ? b_off[n] : 0.f;
    const bool isOff = (n < 288);
    const float* fl = (n < 144) ? f1 : f2;
    const size_t fladd = (size_t)(b * 2 + ((n & 1) ^ 1)) * HW + hw0;
#pragma unroll
    for (int mf = 0; mf < 4; ++mf) {
#pragma unroll
      for (int rr = 0; rr < 4; ++rr) {
        const int px = m_base + mf * 16 + l4 * 4 + rr;
        const float v = acc[mf][f][rr] + bias;
        float val;
        if (isOff) {
          const float e = __expf(2.f * v);
          val = 10.f * (1.f - 2.f / (e + 1.f)) + fl[fladd + px];
        } else {
          val = 1.f / (1.f + __expf(-v));
        }
        so[px * 456 + n] = (_Float16)val;
      }
    }
  }
  __syncthreads();
  for (int T = tid; T < 4608; T += 512) {
    const int px = T / 36, c = T - px * 36;
    const half8 v = *(const half8*)(so + px * 456 + c * 8);
    *(half8*)(off_pm + ((size_t)b * HW + hw0 + px) * 288 + c * 8) = v;
  }
  for (int T = tid; T < 2304; T += 512) {
    const int px = T / 18, c = T - px * 18;
    const half8 v = *(const half8*)(so + px * 456 + 288 + c * 8);
    *(half8*)(mask_pm + ((size_t)b * HW + hw0 + px) * 144 + c * 8) = v;
  }
}

// ---------------- kernel 2: modulated deformable conv (unchanged, round-15) ---------------
__global__ __launch_bounds__(256, 4) void k_deform2(
    const _Float16* __restrict__ featT, const _Float16* __restrict__ off_pm,
    const _Float16* __restrict__ mask_pm, const _Float16* __restrict__ wH,
    const float* __restrict__ dcb, float* __restrict__ out) {
  __shared__ __align__(16) char smem[16 * 1160 * 2];
  _Float16* sm = (_Float16*)smem;
  float* red = (float*)smem;
  const int w0  = blockIdx.x * 16;
  const int h   = blockIdx.y;
  const int b   = blockIdx.z;
  const int tid = (int)threadIdx.x;
  const int lane = tid & 63, wid = tid >> 6;
  const int l15 = lane & 15, l4 = lane >> 4;

  half2v offv[9];
  _Float16 mkv[9];
#pragma unroll
  for (int i = 0; i < 9; ++i) {
    const int p   = tid + i * 256;
    const int pix = p / 144;
    const int r   = p - pix * 144;
    const int w   = w0 + pix;
    const int hw  = h * Ww + w;
    offv[i] = *(const half2v*)(off_pm + ((size_t)b * HW + hw) * 288 + 2 * r);
    mkv[i]  = mask_pm[((size_t)b * HW + hw) * 144 + r];
  }
#pragma unroll
  for (int i = 0; i < 9; ++i) {
    const int p   = tid + i * 256;
    const int pix = p / 144;
    const int r   = p - pix * 144;
    const int g   = r / 9;
    const int k   = r - g * 9;
    const int w   = w0 + pix;
    const float mk = (float)mkv[i];
    const int ki = (k >= 6) ? 2 : (k >= 3 ? 1 : 0);
    const int kj = k - 3 * ki;
    const float py = (float)(h - 1 + ki) + (float)offv[i][0];
    const float px = (float)(w - 1 + kj) + (float)offv[i][1];
    const float y0f = floorf(py), x0f = floorf(px);
    const int y0 = (int)y0f, x0 = (int)x0f;
    const float ly = py - y0f, lx = px - x0f;
    const float hy = 1.f - ly, hx = 1.f - lx;
    const int y1 = y0 + 1, x1 = x0 + 1;
    const bool vy0 = (unsigned)y0 < (unsigned)Hh, vy1 = (unsigned)y1 < (unsigned)Hh;
    const bool vx0 = (unsigned)x0 < (unsigned)Ww, vx1 = (unsigned)x1 < (unsigned)Ww;
    const float w00 = (vy0 && vx0) ? hy * hx : 0.f;
    const float w01 = (vy0 && vx1) ? hy * lx : 0.f;
    const float w10 = (vy1 && vx0) ? ly * hx : 0.f;
    const float w11 = (vy1 && vx1) ? ly * lx : 0.f;
    const int cy0 = min(max(y0, 0), Hh - 1), cy1 = min(max(y1, 0), Hh - 1);
    const int cx0 = min(max(x0, 0), Ww - 1), cx1 = min(max(x1, 0), Ww - 1);
    const _Float16* gbase = featT + ((size_t)(b * 16 + g) * HW) * 8;
    const half8 s00 = *(const half8*)(gbase + (cy0 * Ww + cx0) * 8);
    const half8 s01 = *(const half8*)(gbase + (cy0 * Ww + cx1) * 8);
    const half8 s10 = *(const half8*)(gbase + (cy1 * Ww + cx0) * 8);
    const half8 s11 = *(const half8*)(gbase + (cy1 * Ww + cx1) * 8);
    half8 v = s00 * splat8(w00) + s01 * splat8(w01) + s10 * splat8(w10) + s11 * splat8(w11);
    v = v * splat8(mk);
    const int swz = (g ^ (k & 7)) << 3;
    *(half8*)(sm + pix * 1160 + k * 128 + swz) = v;
  }
  __syncthreads();

  f32x4 acc[4];
#pragma unroll
  for (int nf = 0; nf < 4; ++nf) acc[nf] = (f32x4){0.f, 0.f, 0.f, 0.f};
#pragma unroll
  for (int j = 0; j < 9; ++j) {
    const int s  = wid * 9 + j;
    const int k  = s >> 2;
    const int cg = s & 3;
    const int gidx = cg * 4 + l4;
    const half8 af = *(const half8*)(sm + l15 * 1160 + k * 128 + ((gidx ^ (k & 7)) << 3));
    const int koff = s * 32 + l4 * 8;
#pragma unroll
    for (int nf = 0; nf < 4; ++nf) {
      const half8 bf = *(const half8*)(wH + (nf * 16 + l15) * 1152 + koff);
      acc[nf] = __builtin_amdgcn_mfma_f32_16x16x32_f16(af, bf, acc[nf], 0, 0, 0);
    }
  }
  __syncthreads();
#pragma unroll
  for (int nf = 0; nf < 4; ++nf)
#pragma unroll
    for (int rr = 0; rr < 4; ++rr)
      red[(wid * 16 + l4 * 4 + rr) * 66 + nf * 16 + l15] = acc[nf][rr];
  __syncthreads();

  const int m  = tid & 15;
  const int ng = tid >> 4;
#pragma unroll
  for (int i = 0; i < 4; ++i) {
    const int n = ng + 16 * i;
    float val = red[(0 * 16 + m) * 66 + n] + red[(1 * 16 + m) * 66 + n] +
                red[(2 * 16 + m) * 66 + n] + red[(3 * 16 + m) * 66 + n];
    out[(size_t)(b * 64 + n) * HW + h * Ww + w0 + m] = val + dcb[n];
  }
}

extern "C" void kernel_launch(void* const* d_in, const int* in_sizes, int n_in,
                              void* d_out, int out_size, void* d_ws, size_t ws_size,
                              hipStream_t stream) {
  const float* extra = (const float*)d_in[0];
  const float* f1    = (const float*)d_in[1];
  const float* f2    = (const float*)d_in[2];
  const float* fp    = (const float*)d_in[3];
  const float* fn2   = (const float*)d_in[4];
  const float* w_off = (const float*)d_in[5];
  const float* b_off = (const float*)d_in[6];
  const float* dcw   = (const float*)d_in[7];
  const float* dcb   = (const float*)d_in[8];
  float* out = (float*)d_out;

  // ws layout (~40 MB)
  _Float16* off_pm  = (_Float16*)d_ws;                   // 2*HW*288 fp16
  _Float16* mask_pm = off_pm + (size_t)2 * 288 * HW;     // 2*HW*144 fp16
  _Float16* featT   = mask_pm + (size_t)2 * 144 * HW;    // 2*16*HW*8 fp16
  _Float16* BpT2    = featT + (size_t)2 * 128 * HW;      // 903168 fp16 (63 slices)
  _Float16* wH      = BpT2 + 903168;                     // 73728 fp16

  hipLaunchKernelGGL(k_prep_all, dim3(3944), dim3(256), 0, stream,
                     dcw, w_off, fp, fn2, wH, BpT2, featT);
  hipLaunchKernelGGL(k_offconv_mfma, dim3(128, 2), dim3(512), 0, stream,
                     extra, f1, f2, BpT2, b_off, off_pm, mask_pm);
  hipLaunchKernelGGL(k_deform2, dim3(8, 128, 2), dim3(256), 0, stream,
                     featT, off_pm, mask_pm, wH, dcb, out);
}